// Round 7
// baseline (204.084 us; speedup 1.0000x reference)
//
#include <hip/hip_runtime.h>
#include <hip/hip_bf16.h>
#include <cstdint>

#define NCLOUDS 16
#define N_PER   2048
#define KNN_K   16
#define CAP     48

typedef unsigned long long u64;

#define INFF __builtin_inff()

// ---------------------------------------------------------------------------
// KNN v7: grid = 512 blocks (16 clouds x 32 qblocks, 64 queries each) = 2/CU.
// Block = 512 thr = 8 waves = 4 pairs. Wave half H = wave&1 holds candidates
// H*1024 .. H*1024+1023, SIXTEEN per lane in registers (c = H*1024+jj*64+lane;
// ~105 live VGPRs fits the 128 allocator cap -> no spill, 4 waves/SIMD; the
// 32-cand/lane variants v4-v6 all spilled). Pair pr = wave>>1 handles queries
// pr*16..pr*16+15, two per iteration (ILP-2).
// Pass 1: per-lane min of dot-form e = |c|^2 - 2 q.c (3 fma + min per cand);
// per-wave 64-lane bitonic sort of lane minima; sorted 16-smallest to LDS.
// Threshold: exact 16th of the two sorted lists' union via the two-array
// merge formula min_i max(A[i-1], B[15-i]); upper bound on true 16th-NN d2
// (16 distinct actual d2 at/below it); *(1+1e-5)+1e-4 covers dot-form
// rounding. Pass 2: exact reference-association d2, collect (d2,idx) u64
// (both waves -> shared per-query buf via LDS atomics). Select: each wave of
// the pair sorts one query's buf (64-lane u64 bitonic); lanes 0..15 emit
// exact (d2 asc, idx asc) = jax.lax.top_k tie order.
// ---------------------------------------------------------------------------
__global__ __launch_bounds__(512) void knn_kernel(const float* __restrict__ pos,
                                                  int* __restrict__ knn_out)
{
    __shared__ float qshare[3][64];
    __shared__ float smA[4][2][2][16];   // [pair][half][query01][rank]
    __shared__ u64   buf[4][2][CAP];     // [pair][query01][slot]
    __shared__ int   cnt[4][2];

    const int cloud = blockIdx.x >> 5;
    const int qblk  = blockIdx.x & 31;
    const int tid   = threadIdx.x;
    const int wave  = tid >> 6;
    const int lane  = tid & 63;
    const int H     = wave & 1;
    const int pr    = wave >> 1;

    const int b0 = cloud * N_PER;

    if (tid < 64) {
        const float* qp = pos + (size_t)(b0 + qblk * 64 + tid) * 3;
        qshare[0][tid] = qp[0];
        qshare[1][tid] = qp[1];
        qshare[2][tid] = qp[2];
    }
    if (tid < 8) ((int*)cnt)[tid] = 0;

    // 16 candidates per lane, registers only (static indexing throughout)
    float cx[16], cy[16], cz[16], sc[16];
#pragma unroll
    for (int jj = 0; jj < 16; ++jj) {
        const int c = H * 1024 + jj * 64 + lane;
        const float* p = pos + (size_t)(b0 + c) * 3;
        cx[jj] = p[0]; cy[jj] = p[1]; cz[jj] = p[2];
        sc[jj] = fmaf(cz[jj], cz[jj], fmaf(cy[jj], cy[jj], cx[jj] * cx[jj]));
    }
    __syncthreads();

#pragma unroll 1
    for (int t = 0; t < 8; ++t) {
        const int q0i = pr * 16 + 2 * t;
        const int q1i = q0i + 1;
        const float Q0x = qshare[0][q0i], Q0y = qshare[1][q0i], Q0z = qshare[2][q0i];
        const float Q1x = qshare[0][q1i], Q1y = qshare[1][q1i], Q1z = qshare[2][q1i];

        // ---- pass 1 (ILP-2): per-lane min of dot-form distances ----
        const float A0x = -2.0f * Q0x, A0y = -2.0f * Q0y, A0z = -2.0f * Q0z;
        const float A1x = -2.0f * Q1x, A1y = -2.0f * Q1y, A1z = -2.0f * Q1z;
        const float qq0 = fmaf(Q0z, Q0z, fmaf(Q0y, Q0y, Q0x * Q0x));
        const float qq1 = fmaf(Q1z, Q1z, fmaf(Q1y, Q1y, Q1x * Q1x));
        float mn0 = INFF, mn1 = INFF;
#pragma unroll
        for (int jj = 0; jj < 16; ++jj) {
            float e0 = fmaf(cx[jj], A0x, sc[jj]);
            float e1 = fmaf(cx[jj], A1x, sc[jj]);
            e0 = fmaf(cy[jj], A0y, e0);  e1 = fmaf(cy[jj], A1y, e1);
            e0 = fmaf(cz[jj], A0z, e0);  e1 = fmaf(cz[jj], A1z, e1);
            mn0 = fminf(mn0, e0);        mn1 = fminf(mn1, e1);
        }

        // ---- per-wave bitonic ascending sort of 64 lane minima (ILP-2) ----
        float v0 = mn0, v1 = mn1;
#pragma unroll
        for (int k = 2; k <= 64; k <<= 1) {
#pragma unroll
            for (int j = k >> 1; j >= 1; j >>= 1) {
                const float o0 = __shfl_xor(v0, j);
                const float o1 = __shfl_xor(v1, j);
                const bool keepmin = (((lane & j) == 0) == ((lane & k) == 0));
                v0 = keepmin ? fminf(v0, o0) : fmaxf(v0, o0);
                v1 = keepmin ? fminf(v1, o1) : fmaxf(v1, o1);
            }
        }
        if (lane < 16) {
            smA[pr][H][0][lane] = v0;
            smA[pr][H][1][lane] = v1;
        }
        __syncthreads();

        // ---- exact union-16th of the two sorted 16-lists (merge formula) ----
        float c0 = INFF, c1 = INFF;
        if (lane <= 16) {
            const float a0 = (lane > 0)  ? smA[pr][0][0][lane - 1]  : -INFF;
            const float b0v = (lane < 16) ? smA[pr][1][0][15 - lane] : -INFF;
            c0 = fmaxf(a0, b0v);
            const float a1 = (lane > 0)  ? smA[pr][0][1][lane - 1]  : -INFF;
            const float b1v = (lane < 16) ? smA[pr][1][1][15 - lane] : -INFF;
            c1 = fmaxf(a1, b1v);
        }
#pragma unroll
        for (int j = 1; j <= 32; j <<= 1) {
            c0 = fminf(c0, __shfl_xor(c0, j));
            c1 = fminf(c1, __shfl_xor(c1, j));
        }
        const float T0 = (c0 + qq0) * (1.0f + 1e-5f) + 1e-4f;
        const float T1 = (c1 + qq1) * (1.0f + 1e-5f) + 1e-4f;

        // ---- pass 2 (ILP-2): exact d2 (reference association), collect ----
#pragma unroll
        for (int jj = 0; jj < 16; ++jj) {
            const int c = H * 1024 + jj * 64 + lane;
            const float dx0 = __fsub_rn(Q0x, cx[jj]);
            const float dy0 = __fsub_rn(Q0y, cy[jj]);
            const float dz0 = __fsub_rn(Q0z, cz[jj]);
            const float d20 = __fadd_rn(__fadd_rn(__fmul_rn(dx0, dx0), __fmul_rn(dy0, dy0)),
                                        __fmul_rn(dz0, dz0));
            if (d20 <= T0) {
                const int slot = atomicAdd(&cnt[pr][0], 1);
                if (slot < CAP)
                    buf[pr][0][slot] = ((u64)__float_as_uint(d20) << 32) | (unsigned)c;
            }
            const float dx1 = __fsub_rn(Q1x, cx[jj]);
            const float dy1 = __fsub_rn(Q1y, cy[jj]);
            const float dz1 = __fsub_rn(Q1z, cz[jj]);
            const float d21 = __fadd_rn(__fadd_rn(__fmul_rn(dx1, dx1), __fmul_rn(dy1, dy1)),
                                        __fmul_rn(dz1, dz1));
            if (d21 <= T1) {
                const int slot = atomicAdd(&cnt[pr][1], 1);
                if (slot < CAP)
                    buf[pr][1][slot] = ((u64)__float_as_uint(d21) << 32) | (unsigned)c;
            }
        }
        __syncthreads();

        // ---- select: wave H sorts query (q0i + H)'s buffer ----
        const int n = min(cnt[pr][H], CAP);
        u64 key = (lane < n) ? buf[pr][H][lane] : ~0ULL;
#pragma unroll
        for (int k = 2; k <= 64; k <<= 1) {
#pragma unroll
            for (int j = k >> 1; j >= 1; j >>= 1) {
                const u64 o = __shfl_xor(key, j);
                const bool keepmin = (((lane & j) == 0) == ((lane & k) == 0));
                const u64 lo = key < o ? key : o;
                const u64 hi = key < o ? o : key;
                key = keepmin ? lo : hi;
            }
        }
        if (lane < KNN_K)
            knn_out[((size_t)b0 + qblk * 64 + q0i + H) * KNN_K + lane] =
                b0 + (int)(unsigned)(key & 0xffffffffu);
        if (lane == 0) cnt[pr][H] = 0;
        __syncthreads();
    }
}

// ---------------------------------------------------------------------------
// Per-point pre-projection: w[p] = ba + hin[p]@Wa_h + pos[p]@Wa_s,
// v[p] = pos[p]@Wa_s. (x@Wa with x=concat(h_j, p_j-p_i) == w[j] - v[i].)
// ---------------------------------------------------------------------------
template <int CH>
__global__ __launch_bounds__(256) void pre_kernel(
    const float* __restrict__ pos, const float* __restrict__ hin,
    const float* __restrict__ Wa, const float* __restrict__ ba,
    float* __restrict__ w, float* __restrict__ v)
{
    const int gth = blockIdx.x * 256 + threadIdx.x;
    const int p   = gth >> 3;
    const int i8  = gth & 7;
    const float4* Wa4 = (const float4*)Wa;
    const float4* ba4 = (const float4*)ba;

    float4 acc = ba4[i8];
    const float* hrow = hin + (size_t)p * CH;
#pragma unroll
    for (int d = 0; d < CH; ++d) {
        const float h = hrow[d];
        const float4 wr = Wa4[d * 8 + i8];
        acc.x = fmaf(h, wr.x, acc.x);
        acc.y = fmaf(h, wr.y, acc.y);
        acc.z = fmaf(h, wr.z, acc.z);
        acc.w = fmaf(h, wr.w, acc.w);
    }
    float4 vs = make_float4(0.f, 0.f, 0.f, 0.f);
    const float* prow = pos + (size_t)p * 3;
#pragma unroll
    for (int d = 0; d < 3; ++d) {
        const float pd = prow[d];
        const float4 wr = Wa4[(CH + d) * 8 + i8];
        vs.x = fmaf(pd, wr.x, vs.x);
        vs.y = fmaf(pd, wr.y, vs.y);
        vs.z = fmaf(pd, wr.z, vs.z);
        vs.w = fmaf(pd, wr.w, vs.w);
    }
    ((float4*)w)[(size_t)p * 8 + i8] =
        make_float4(acc.x + vs.x, acc.y + vs.y, acc.z + vs.z, acc.w + vs.w);
    ((float4*)v)[(size_t)p * 8 + i8] = vs;
}

// ---------------------------------------------------------------------------
// Edge-MLP layer: lane = edge (p,k); hid = relu(w[j]-v[p]); o[32] register
// accumulator iterated c-outer so Wb reads are CONTIGUOUS wave-uniform rows
// (s_load_dwordx16; v6's c2-inner made them stride-32 columns). Butterfly max
// over the 16 edge-lanes at the end; outer relu.
// ---------------------------------------------------------------------------
__global__ __launch_bounds__(256) void layer_kernel(
    const int*   __restrict__ knn,
    const float* __restrict__ Wb, const float* __restrict__ bb,
    const float* __restrict__ w,  const float* __restrict__ v,
    float* __restrict__ hout)
{
    const int gth = blockIdx.x * 256 + threadIdx.x;
    const int p = gth >> 4;
    const int k = gth & 15;
    const int j = knn[gth];

    const float4* w4 = (const float4*)w;
    const float4* v4 = (const float4*)v;

    float hid[32];
#pragma unroll
    for (int i = 0; i < 8; ++i) {
        const float4 a = w4[(size_t)j * 8 + i];
        const float4 b = v4[(size_t)p * 8 + i];
        hid[4 * i + 0] = fmaxf(a.x - b.x, 0.0f);
        hid[4 * i + 1] = fmaxf(a.y - b.y, 0.0f);
        hid[4 * i + 2] = fmaxf(a.z - b.z, 0.0f);
        hid[4 * i + 3] = fmaxf(a.w - b.w, 0.0f);
    }

    float o[32];
#pragma unroll
    for (int c2 = 0; c2 < 32; ++c2) o[c2] = bb[c2];
#pragma unroll
    for (int c = 0; c < 32; ++c) {
        const float hc = hid[c];
        const float* row = Wb + c * 32;   // contiguous, wave-uniform -> s_load
#pragma unroll
        for (int c2 = 0; c2 < 32; ++c2) o[c2] = fmaf(hc, row[c2], o[c2]);
    }

    float out0 = 0.0f, out1 = 0.0f;
#pragma unroll
    for (int c2 = 0; c2 < 32; ++c2) {
        float s = o[c2];
        s = fmaxf(s, __shfl_xor(s, 1));
        s = fmaxf(s, __shfl_xor(s, 2));
        s = fmaxf(s, __shfl_xor(s, 4));
        s = fmaxf(s, __shfl_xor(s, 8));
        if ((c2 & 15) == k) { if (c2 < 16) out0 = s; else out1 = s; }
    }
    hout[(size_t)p * 32 + k]      = fmaxf(out0, 0.0f);
    hout[(size_t)p * 32 + 16 + k] = fmaxf(out1, 0.0f);
}

// ---------------------------------------------------------------------------
// Global max pool over each cloud + linear classifier. 1 block per cloud.
// ---------------------------------------------------------------------------
__global__ __launch_bounds__(256) void pool_kernel(
    const float* __restrict__ h2, const float* __restrict__ Wc,
    const float* __restrict__ bc, float* __restrict__ out)
{
    __shared__ float red[8][32];
    __shared__ float sg[32];
    const int cloud = blockIdx.x;
    const int t = threadIdx.x;
    const int c = t & 31, row = t >> 5;
    float m = 0.0f;  // h2 >= 0 after relu
    for (int p = row; p < N_PER; p += 8)
        m = fmaxf(m, h2[((size_t)cloud * N_PER + p) * 32 + c]);
    red[row][c] = m;
    __syncthreads();
    if (t < 32) {
        float gv = red[0][t];
#pragma unroll
        for (int r = 1; r < 8; ++r) gv = fmaxf(gv, red[r][t]);
        sg[t] = gv;
    }
    __syncthreads();
    if (t < 10) {
        float s = bc[t];
#pragma unroll
        for (int c0 = 0; c0 < 32; ++c0) s = fmaf(sg[c0], Wc[c0 * 10 + t], s);
        out[cloud * 10 + t] = s;
    }
}

extern "C" void kernel_launch(void* const* d_in, const int* in_sizes, int n_in,
                              void* d_out, int out_size, void* d_ws, size_t ws_size,
                              hipStream_t stream)
{
    const float* pos = (const float*)d_in[0];
    const float* W1a = (const float*)d_in[2];
    const float* b1a = (const float*)d_in[3];
    const float* W1b = (const float*)d_in[4];
    const float* b1b = (const float*)d_in[5];
    const float* W2a = (const float*)d_in[6];
    const float* b2a = (const float*)d_in[7];
    const float* W2b = (const float*)d_in[8];
    const float* b2b = (const float*)d_in[9];
    const float* Wc  = (const float*)d_in[10];
    const float* bc  = (const float*)d_in[11];

    int*   knn = (int*)d_ws;                                   // 2 MB
    float* w   = (float*)((char*)d_ws + (size_t)(2  << 20));   // 4 MB
    float* v   = (float*)((char*)d_ws + (size_t)(6  << 20));   // 4 MB
    float* h1  = (float*)((char*)d_ws + (size_t)(10 << 20));   // 4 MB
    float* h2  = h1;   // h1 dead after pre2; layer2 reads only w,v
    float* out = (float*)d_out;

    const int npts = NCLOUDS * N_PER;

    knn_kernel<<<dim3(NCLOUDS * 32), dim3(512), 0, stream>>>(pos, knn);
    pre_kernel<3><<<dim3(npts * 8 / 256), dim3(256), 0, stream>>>(
        pos, pos, W1a, b1a, w, v);
    layer_kernel<<<dim3(npts * KNN_K / 256), dim3(256), 0, stream>>>(
        knn, W1b, b1b, w, v, h1);
    pre_kernel<32><<<dim3(npts * 8 / 256), dim3(256), 0, stream>>>(
        pos, h1, W2a, b2a, w, v);
    layer_kernel<<<dim3(npts * KNN_K / 256), dim3(256), 0, stream>>>(
        knn, W2b, b2b, w, v, h2);
    pool_kernel<<<dim3(NCLOUDS), dim3(256), 0, stream>>>(h2, Wc, bc, out);
}

// Round 9
// 165.284 us; speedup vs baseline: 1.2347x; 1.2347x over previous
//
#include <hip/hip_runtime.h>
#include <hip/hip_bf16.h>
#include <cstdint>

#define NCLOUDS 16
#define N_PER   2048
#define KNN_K   16
#define CAP     48

typedef unsigned long long u64;
#define INFF __builtin_inff()

// ---- cross-lane xor exchange: DPP for 1/2 (VALU pipe), ds_swizzle for
// 4/8/16 (DS pipe, no addr setup), shfl for 32. All exact xor exchanges. ----
template <int J>
__device__ __forceinline__ int ixor(int x) {
    if constexpr (J == 1)
        return __builtin_amdgcn_update_dpp(0, x, 0xB1, 0xF, 0xF, true);   // quad_perm [1,0,3,2]
    else if constexpr (J == 2)
        return __builtin_amdgcn_update_dpp(0, x, 0x4E, 0xF, 0xF, true);   // quad_perm [2,3,0,1]
    else if constexpr (J <= 16)
        return __builtin_amdgcn_ds_swizzle(x, (J << 10) | 0x1F);          // xor-J bitmode
    else
        return __shfl_xor(x, 32);
}
template <int J> __device__ __forceinline__ float fxor(float x) {
    return __int_as_float(ixor<J>(__float_as_int(x)));
}
template <int J> __device__ __forceinline__ u64 uxor(u64 x) {
    const int lo = ixor<J>((int)(x & 0xffffffffULL));
    const int hi = ixor<J>((int)(x >> 32));
    return ((u64)(unsigned)hi << 32) | (unsigned)lo;
}

// 16-lane-group max, all lanes receive result; pure VALU (DPP row ops).
// Valid because after each stage the exchanged groups hold uniform values.
__device__ __forceinline__ float dpp_max16(float x) {
    x = fmaxf(x, __int_as_float(__builtin_amdgcn_update_dpp(0, __float_as_int(x), 0xB1, 0xF, 0xF, true)));
    x = fmaxf(x, __int_as_float(__builtin_amdgcn_update_dpp(0, __float_as_int(x), 0x4E, 0xF, 0xF, true)));
    x = fmaxf(x, __int_as_float(__builtin_amdgcn_update_dpp(0, __float_as_int(x), 0x141, 0xF, 0xF, true))); // row_half_mirror
    x = fmaxf(x, __int_as_float(__builtin_amdgcn_update_dpp(0, __float_as_int(x), 0x140, 0xF, 0xF, true))); // row_mirror
    return x;
}

// ---------------------------------------------------------------------------
// KNN v9 (= v8 with the phase-1 smA indexing fixed to PAIR-LOCAL [2t]/[2t+1];
// v8 wrote global q0=pr*16+2t into a 16-deep dim -> OOB corruption for pr>0).
// Structure: 3 batched phases, 3 barriers/block; DPP/swizzle bitonics; ILP-2.
// Math identical to v7 (passed): wave pairs, 16 cands/lane in regs, dot-form
// pass1 minima, per-wave sorted-16, union-16th merge threshold (+rounding
// margin), exact-d2 collect, u64 bitonic select with top_k tie order.
// ---------------------------------------------------------------------------
__global__ __launch_bounds__(512) void knn_kernel(const float* __restrict__ pos,
                                                  int* __restrict__ knn_out)
{
    __shared__ float qshare[3][64];
    __shared__ float smA[4][2][16][16];   // [pair][half][pair-local query][rank]
    __shared__ u64   buf[4][16][CAP];     // [pair][pair-local query][slot]
    __shared__ int   cnt[4][16];

    const int cloud = blockIdx.x >> 5;
    const int qblk  = blockIdx.x & 31;
    const int tid   = threadIdx.x;
    const int wave  = tid >> 6;
    const int lane  = tid & 63;
    const int H     = wave & 1;
    const int pr    = wave >> 1;

    const int b0 = cloud * N_PER;

    if (tid < 64) {
        const float* qp = pos + (size_t)(b0 + qblk * 64 + tid) * 3;
        qshare[0][tid] = qp[0];
        qshare[1][tid] = qp[1];
        qshare[2][tid] = qp[2];
        ((int*)cnt)[tid] = 0;
    }

    float cx[16], cy[16], cz[16], sc[16];
#pragma unroll
    for (int jj = 0; jj < 16; ++jj) {
        const int c = H * 1024 + jj * 64 + lane;
        const float* p = pos + (size_t)(b0 + c) * 3;
        cx[jj] = p[0]; cy[jj] = p[1]; cz[jj] = p[2];
        sc[jj] = fmaf(cz[jj], cz[jj], fmaf(cy[jj], cy[jj], cx[jj] * cx[jj]));
    }
    __syncthreads();

    // ================= phase 1: scan + sort lane-minima (ILP-2) ============
#pragma unroll 1
    for (int t = 0; t < 8; ++t) {
        const int qg0 = pr * 16 + 2 * t, qg1 = qg0 + 1;   // global query ids
        const float Q0x = qshare[0][qg0], Q0y = qshare[1][qg0], Q0z = qshare[2][qg0];
        const float Q1x = qshare[0][qg1], Q1y = qshare[1][qg1], Q1z = qshare[2][qg1];
        const float A0x = -2.0f * Q0x, A0y = -2.0f * Q0y, A0z = -2.0f * Q0z;
        const float A1x = -2.0f * Q1x, A1y = -2.0f * Q1y, A1z = -2.0f * Q1z;
        float v0 = INFF, v1 = INFF;
#pragma unroll
        for (int jj = 0; jj < 16; ++jj) {
            float e0 = fmaf(cx[jj], A0x, sc[jj]);
            float e1 = fmaf(cx[jj], A1x, sc[jj]);
            e0 = fmaf(cy[jj], A0y, e0);  e1 = fmaf(cy[jj], A1y, e1);
            e0 = fmaf(cz[jj], A0z, e0);  e1 = fmaf(cz[jj], A1z, e1);
            v0 = fminf(v0, e0);          v1 = fminf(v1, e1);
        }
        // bitonic ascending sort of 64 lane minima (both chains)
#define FS(K, J) { const float o0 = fxor<J>(v0), o1 = fxor<J>(v1);              \
                   const bool km = (((lane & J) == 0) == ((lane & K) == 0));    \
                   v0 = km ? fminf(v0, o0) : fmaxf(v0, o0);                     \
                   v1 = km ? fminf(v1, o1) : fmaxf(v1, o1); }
        FS(2,1)
        FS(4,2) FS(4,1)
        FS(8,4) FS(8,2) FS(8,1)
        FS(16,8) FS(16,4) FS(16,2) FS(16,1)
        FS(32,16) FS(32,8) FS(32,4) FS(32,2) FS(32,1)
        FS(64,32) FS(64,16) FS(64,8) FS(64,4) FS(64,2) FS(64,1)
#undef FS
        if (lane < 16) {
            smA[pr][H][2 * t][lane]     = v0;   // PAIR-LOCAL index (v8 bug fix)
            smA[pr][H][2 * t + 1][lane] = v1;
        }
    }
    __syncthreads();

    // ================= phase 2: merge threshold + collect (ILP-2) ==========
#pragma unroll 1
    for (int t = 0; t < 8; ++t) {
        const int q0 = 2 * t, q1 = q0 + 1;           // pair-local query ids
        // union-16th of the two sorted 16-lists: min_i max(A[i-1], B[15-i])
        float a0 = -INFF, a1 = -INFF, b0v = -INFF, b1v = -INFF;
        if (lane > 0 && lane <= 16) {
            a0 = smA[pr][0][q0][lane - 1];
            a1 = smA[pr][0][q1][lane - 1];
        }
        if (lane < 16) {
            b0v = smA[pr][1][q0][15 - lane];
            b1v = smA[pr][1][q1][15 - lane];
        }
        float m0 = (lane <= 16) ? fmaxf(a0, b0v) : INFF;
        float m1 = (lane <= 16) ? fmaxf(a1, b1v) : INFF;
        m0 = fminf(m0, fxor<1>(m0));   m1 = fminf(m1, fxor<1>(m1));
        m0 = fminf(m0, fxor<2>(m0));   m1 = fminf(m1, fxor<2>(m1));
        m0 = fminf(m0, fxor<4>(m0));   m1 = fminf(m1, fxor<4>(m1));
        m0 = fminf(m0, fxor<8>(m0));   m1 = fminf(m1, fxor<8>(m1));
        m0 = fminf(m0, fxor<16>(m0));  m1 = fminf(m1, fxor<16>(m1));
        m0 = fminf(m0, fxor<32>(m0));  m1 = fminf(m1, fxor<32>(m1));

        const int qg0 = pr * 16 + q0, qg1 = pr * 16 + q1;
        const float Q0x = qshare[0][qg0], Q0y = qshare[1][qg0], Q0z = qshare[2][qg0];
        const float Q1x = qshare[0][qg1], Q1y = qshare[1][qg1], Q1z = qshare[2][qg1];
        const float qq0 = fmaf(Q0z, Q0z, fmaf(Q0y, Q0y, Q0x * Q0x));
        const float qq1 = fmaf(Q1z, Q1z, fmaf(Q1y, Q1y, Q1x * Q1x));
        const float T0 = (m0 + qq0) * (1.0f + 1e-5f) + 1e-4f;
        const float T1 = (m1 + qq1) * (1.0f + 1e-5f) + 1e-4f;

        // exact d2 (reference association), collect <= T
#pragma unroll
        for (int jj = 0; jj < 16; ++jj) {
            const int c = H * 1024 + jj * 64 + lane;
            const float dx0 = __fsub_rn(Q0x, cx[jj]);
            const float dy0 = __fsub_rn(Q0y, cy[jj]);
            const float dz0 = __fsub_rn(Q0z, cz[jj]);
            const float d20 = __fadd_rn(__fadd_rn(__fmul_rn(dx0, dx0), __fmul_rn(dy0, dy0)),
                                        __fmul_rn(dz0, dz0));
            if (d20 <= T0) {
                const int slot = atomicAdd(&cnt[pr][q0], 1);
                if (slot < CAP)
                    buf[pr][q0][slot] = ((u64)__float_as_uint(d20) << 32) | (unsigned)c;
            }
            const float dx1 = __fsub_rn(Q1x, cx[jj]);
            const float dy1 = __fsub_rn(Q1y, cy[jj]);
            const float dz1 = __fsub_rn(Q1z, cz[jj]);
            const float d21 = __fadd_rn(__fadd_rn(__fmul_rn(dx1, dx1), __fmul_rn(dy1, dy1)),
                                        __fmul_rn(dz1, dz1));
            if (d21 <= T1) {
                const int slot = atomicAdd(&cnt[pr][q1], 1);
                if (slot < CAP)
                    buf[pr][q1][slot] = ((u64)__float_as_uint(d21) << 32) | (unsigned)c;
            }
        }
    }
    __syncthreads();

    // ================= phase 3: select top-16 (ILP-2, 4 pairs/wave) ========
#pragma unroll 1
    for (int s = 0; s < 4; ++s) {
        const int q0 = H * 8 + 2 * s, q1 = q0 + 1;   // wave's select queries
        const int n0 = min(cnt[pr][q0], CAP);
        const int n1 = min(cnt[pr][q1], CAP);
        u64 k0 = (lane < n0) ? buf[pr][q0][lane] : ~0ULL;
        u64 k1 = (lane < n1) ? buf[pr][q1][lane] : ~0ULL;
#define US(K, J) { const u64 o0 = uxor<J>(k0), o1 = uxor<J>(k1);                \
                   const bool km = (((lane & J) == 0) == ((lane & K) == 0));    \
                   const u64 l0 = k0 < o0 ? k0 : o0, h0 = k0 < o0 ? o0 : k0;    \
                   k0 = km ? l0 : h0;                                           \
                   const u64 l1 = k1 < o1 ? k1 : o1, h1 = k1 < o1 ? o1 : k1;    \
                   k1 = km ? l1 : h1; }
        US(2,1)
        US(4,2) US(4,1)
        US(8,4) US(8,2) US(8,1)
        US(16,8) US(16,4) US(16,2) US(16,1)
        US(32,16) US(32,8) US(32,4) US(32,2) US(32,1)
        US(64,32) US(64,16) US(64,8) US(64,4) US(64,2) US(64,1)
#undef US
        if (lane < KNN_K) {
            knn_out[((size_t)b0 + qblk * 64 + pr * 16 + q0) * KNN_K + lane] =
                b0 + (int)(unsigned)(k0 & 0xffffffffu);
            knn_out[((size_t)b0 + qblk * 64 + pr * 16 + q1) * KNN_K + lane] =
                b0 + (int)(unsigned)(k1 & 0xffffffffu);
        }
    }
}

// ---------------------------------------------------------------------------
// Per-point pre-projection: w[p] = ba + hin[p]@Wa_h + pos[p]@Wa_s,
// v[p] = pos[p]@Wa_s. (x@Wa with x=concat(h_j, p_j-p_i) == w[j] - v[i].)
// ---------------------------------------------------------------------------
template <int CH>
__global__ __launch_bounds__(256) void pre_kernel(
    const float* __restrict__ pos, const float* __restrict__ hin,
    const float* __restrict__ Wa, const float* __restrict__ ba,
    float* __restrict__ w, float* __restrict__ v)
{
    const int gth = blockIdx.x * 256 + threadIdx.x;
    const int p   = gth >> 3;
    const int i8  = gth & 7;
    const float4* Wa4 = (const float4*)Wa;
    const float4* ba4 = (const float4*)ba;

    float4 acc = ba4[i8];
    const float* hrow = hin + (size_t)p * CH;
#pragma unroll
    for (int d = 0; d < CH; ++d) {
        const float h = hrow[d];
        const float4 wr = Wa4[d * 8 + i8];
        acc.x = fmaf(h, wr.x, acc.x);
        acc.y = fmaf(h, wr.y, acc.y);
        acc.z = fmaf(h, wr.z, acc.z);
        acc.w = fmaf(h, wr.w, acc.w);
    }
    float4 vs = make_float4(0.f, 0.f, 0.f, 0.f);
    const float* prow = pos + (size_t)p * 3;
#pragma unroll
    for (int d = 0; d < 3; ++d) {
        const float pd = prow[d];
        const float4 wr = Wa4[(CH + d) * 8 + i8];
        vs.x = fmaf(pd, wr.x, vs.x);
        vs.y = fmaf(pd, wr.y, vs.y);
        vs.z = fmaf(pd, wr.z, vs.z);
        vs.w = fmaf(pd, wr.w, vs.w);
    }
    ((float4*)w)[(size_t)p * 8 + i8] =
        make_float4(acc.x + vs.x, acc.y + vs.y, acc.z + vs.z, acc.w + vs.w);
    ((float4*)v)[(size_t)p * 8 + i8] = vs;
}

// ---------------------------------------------------------------------------
// Edge-MLP layer: lane = edge (p,k); hid = relu(w[j]-v[p]); o[32] register
// accumulator, Wb read as contiguous wave-uniform rows (s_load). Max over the
// 16 edge-lanes via DPP (VALU pipe).
// ---------------------------------------------------------------------------
__global__ __launch_bounds__(256) void layer_kernel(
    const int*   __restrict__ knn,
    const float* __restrict__ Wb, const float* __restrict__ bb,
    const float* __restrict__ w,  const float* __restrict__ v,
    float* __restrict__ hout)
{
    const int gth = blockIdx.x * 256 + threadIdx.x;
    const int p = gth >> 4;
    const int k = gth & 15;
    const int j = knn[gth];

    const float4* w4 = (const float4*)w;
    const float4* v4 = (const float4*)v;

    float hid[32];
#pragma unroll
    for (int i = 0; i < 8; ++i) {
        const float4 a = w4[(size_t)j * 8 + i];
        const float4 b = v4[(size_t)p * 8 + i];
        hid[4 * i + 0] = fmaxf(a.x - b.x, 0.0f);
        hid[4 * i + 1] = fmaxf(a.y - b.y, 0.0f);
        hid[4 * i + 2] = fmaxf(a.z - b.z, 0.0f);
        hid[4 * i + 3] = fmaxf(a.w - b.w, 0.0f);
    }

    float o[32];
#pragma unroll
    for (int c2 = 0; c2 < 32; ++c2) o[c2] = bb[c2];
#pragma unroll
    for (int c = 0; c < 32; ++c) {
        const float hc = hid[c];
        const float* row = Wb + c * 32;   // contiguous, wave-uniform -> s_load
#pragma unroll
        for (int c2 = 0; c2 < 32; ++c2) o[c2] = fmaf(hc, row[c2], o[c2]);
    }

    float out0 = 0.0f, out1 = 0.0f;
#pragma unroll
    for (int c2 = 0; c2 < 32; ++c2) {
        const float s = dpp_max16(o[c2]);
        if ((c2 & 15) == k) { if (c2 < 16) out0 = s; else out1 = s; }
    }
    hout[(size_t)p * 32 + k]      = fmaxf(out0, 0.0f);
    hout[(size_t)p * 32 + 16 + k] = fmaxf(out1, 0.0f);
}

// ---------------------------------------------------------------------------
// Global max pool over each cloud + linear classifier. 1 block per cloud.
// ---------------------------------------------------------------------------
__global__ __launch_bounds__(256) void pool_kernel(
    const float* __restrict__ h2, const float* __restrict__ Wc,
    const float* __restrict__ bc, float* __restrict__ out)
{
    __shared__ float red[8][32];
    __shared__ float sg[32];
    const int cloud = blockIdx.x;
    const int t = threadIdx.x;
    const int c = t & 31, row = t >> 5;
    float m = 0.0f;  // h2 >= 0 after relu
    for (int p = row; p < N_PER; p += 8)
        m = fmaxf(m, h2[((size_t)cloud * N_PER + p) * 32 + c]);
    red[row][c] = m;
    __syncthreads();
    if (t < 32) {
        float gv = red[0][t];
#pragma unroll
        for (int r = 1; r < 8; ++r) gv = fmaxf(gv, red[r][t]);
        sg[t] = gv;
    }
    __syncthreads();
    if (t < 10) {
        float s = bc[t];
#pragma unroll
        for (int c0 = 0; c0 < 32; ++c0) s = fmaf(sg[c0], Wc[c0 * 10 + t], s);
        out[cloud * 10 + t] = s;
    }
}

extern "C" void kernel_launch(void* const* d_in, const int* in_sizes, int n_in,
                              void* d_out, int out_size, void* d_ws, size_t ws_size,
                              hipStream_t stream)
{
    const float* pos = (const float*)d_in[0];
    const float* W1a = (const float*)d_in[2];
    const float* b1a = (const float*)d_in[3];
    const float* W1b = (const float*)d_in[4];
    const float* b1b = (const float*)d_in[5];
    const float* W2a = (const float*)d_in[6];
    const float* b2a = (const float*)d_in[7];
    const float* W2b = (const float*)d_in[8];
    const float* b2b = (const float*)d_in[9];
    const float* Wc  = (const float*)d_in[10];
    const float* bc  = (const float*)d_in[11];

    int*   knn = (int*)d_ws;                                   // 2 MB
    float* w   = (float*)((char*)d_ws + (size_t)(2  << 20));   // 4 MB
    float* v   = (float*)((char*)d_ws + (size_t)(6  << 20));   // 4 MB
    float* h1  = (float*)((char*)d_ws + (size_t)(10 << 20));   // 4 MB
    float* h2  = h1;   // h1 dead after pre2; layer2 reads only w,v
    float* out = (float*)d_out;

    const int npts = NCLOUDS * N_PER;

    knn_kernel<<<dim3(NCLOUDS * 32), dim3(512), 0, stream>>>(pos, knn);
    pre_kernel<3><<<dim3(npts * 8 / 256), dim3(256), 0, stream>>>(
        pos, pos, W1a, b1a, w, v);
    layer_kernel<<<dim3(npts * KNN_K / 256), dim3(256), 0, stream>>>(
        knn, W1b, b1b, w, v, h1);
    pre_kernel<32><<<dim3(npts * 8 / 256), dim3(256), 0, stream>>>(
        pos, h1, W2a, b2a, w, v);
    layer_kernel<<<dim3(npts * KNN_K / 256), dim3(256), 0, stream>>>(
        knn, W2b, b2b, w, v, h2);
    pool_kernel<<<dim3(NCLOUDS), dim3(256), 0, stream>>>(h2, Wc, bc, out);
}

// Round 10
// 163.914 us; speedup vs baseline: 1.2451x; 1.0084x over previous
//
#include <hip/hip_runtime.h>
#include <hip/hip_bf16.h>
#include <cstdint>

#define NCLOUDS 16
#define N_PER   2048
#define KNN_K   16
#define CAP     48

typedef unsigned long long u64;
#define INFF __builtin_inff()

// ---- cross-lane xor exchange: DPP for 1/2 (VALU pipe), ds_swizzle for
// 4/8/16 (DS pipe, no addr setup), shfl for 32. All exact xor exchanges. ----
template <int J>
__device__ __forceinline__ int ixor(int x) {
    if constexpr (J == 1)
        return __builtin_amdgcn_update_dpp(0, x, 0xB1, 0xF, 0xF, true);   // quad_perm [1,0,3,2]
    else if constexpr (J == 2)
        return __builtin_amdgcn_update_dpp(0, x, 0x4E, 0xF, 0xF, true);   // quad_perm [2,3,0,1]
    else if constexpr (J <= 16)
        return __builtin_amdgcn_ds_swizzle(x, (J << 10) | 0x1F);          // xor-J bitmode
    else
        return __shfl_xor(x, 32);
}
template <int J> __device__ __forceinline__ float fxor(float x) {
    return __int_as_float(ixor<J>(__float_as_int(x)));
}
template <int J> __device__ __forceinline__ u64 uxor(u64 x) {
    const int lo = ixor<J>((int)(x & 0xffffffffULL));
    const int hi = ixor<J>((int)(x >> 32));
    return ((u64)(unsigned)hi << 32) | (unsigned)lo;
}

// 16-lane-group max, all lanes receive result; pure VALU (DPP row ops).
__device__ __forceinline__ float dpp_max16(float x) {
    x = fmaxf(x, __int_as_float(__builtin_amdgcn_update_dpp(0, __float_as_int(x), 0xB1, 0xF, 0xF, true)));
    x = fmaxf(x, __int_as_float(__builtin_amdgcn_update_dpp(0, __float_as_int(x), 0x4E, 0xF, 0xF, true)));
    x = fmaxf(x, __int_as_float(__builtin_amdgcn_update_dpp(0, __float_as_int(x), 0x141, 0xF, 0xF, true))); // row_half_mirror
    x = fmaxf(x, __int_as_float(__builtin_amdgcn_update_dpp(0, __float_as_int(x), 0x140, 0xF, 0xF, true))); // row_mirror
    return x;
}

// ---------------------------------------------------------------------------
// KNN v10 (= v9 with 32 queries/block): grid = 1024 blocks (16 clouds x 64
// qblocks) -> 4 blocks/CU x 8 waves = 32 waves/CU (v9: 2 blocks/CU, Occ 34%).
// LDS ~16.6KB/block so 4 blocks fit; VGPR 56 allows 8 waves/SIMD.
// Same math as v9 (passed): wave pairs hold the cloud in regs (16 cands/
// lane), dot-form pass1 minima, per-wave sorted-16, union-16th merge
// threshold (+rounding margin), exact-d2 collect, u64 bitonic select with
// jax.lax.top_k tie order. 3 batched phases, 3 barriers.
// ---------------------------------------------------------------------------
__global__ __launch_bounds__(512) void knn_kernel(const float* __restrict__ pos,
                                                  int* __restrict__ knn_out)
{
    __shared__ float qshare[3][32];
    __shared__ float smA[4][2][8][16];    // [pair][half][pair-local query][rank]
    __shared__ u64   buf[4][8][CAP];      // [pair][pair-local query][slot]
    __shared__ int   cnt[4][8];

    const int cloud = blockIdx.x >> 6;
    const int qblk  = blockIdx.x & 63;    // 64 qblocks/cloud, 32 queries each
    const int tid   = threadIdx.x;
    const int wave  = tid >> 6;
    const int lane  = tid & 63;
    const int H     = wave & 1;
    const int pr    = wave >> 1;

    const int b0 = cloud * N_PER;

    if (tid < 32) {
        const float* qp = pos + (size_t)(b0 + qblk * 32 + tid) * 3;
        qshare[0][tid] = qp[0];
        qshare[1][tid] = qp[1];
        qshare[2][tid] = qp[2];
        ((int*)cnt)[tid] = 0;
    }

    float cx[16], cy[16], cz[16], sc[16];
#pragma unroll
    for (int jj = 0; jj < 16; ++jj) {
        const int c = H * 1024 + jj * 64 + lane;
        const float* p = pos + (size_t)(b0 + c) * 3;
        cx[jj] = p[0]; cy[jj] = p[1]; cz[jj] = p[2];
        sc[jj] = fmaf(cz[jj], cz[jj], fmaf(cy[jj], cy[jj], cx[jj] * cx[jj]));
    }
    __syncthreads();

    // ================= phase 1: scan + sort lane-minima (ILP-2) ============
#pragma unroll 1
    for (int t = 0; t < 4; ++t) {
        const int qg0 = pr * 8 + 2 * t, qg1 = qg0 + 1;   // block-local query ids
        const float Q0x = qshare[0][qg0], Q0y = qshare[1][qg0], Q0z = qshare[2][qg0];
        const float Q1x = qshare[0][qg1], Q1y = qshare[1][qg1], Q1z = qshare[2][qg1];
        const float A0x = -2.0f * Q0x, A0y = -2.0f * Q0y, A0z = -2.0f * Q0z;
        const float A1x = -2.0f * Q1x, A1y = -2.0f * Q1y, A1z = -2.0f * Q1z;
        float v0 = INFF, v1 = INFF;
#pragma unroll
        for (int jj = 0; jj < 16; ++jj) {
            float e0 = fmaf(cx[jj], A0x, sc[jj]);
            float e1 = fmaf(cx[jj], A1x, sc[jj]);
            e0 = fmaf(cy[jj], A0y, e0);  e1 = fmaf(cy[jj], A1y, e1);
            e0 = fmaf(cz[jj], A0z, e0);  e1 = fmaf(cz[jj], A1z, e1);
            v0 = fminf(v0, e0);          v1 = fminf(v1, e1);
        }
        // bitonic ascending sort of 64 lane minima (both chains)
#define FS(K, J) { const float o0 = fxor<J>(v0), o1 = fxor<J>(v1);              \
                   const bool km = (((lane & J) == 0) == ((lane & K) == 0));    \
                   v0 = km ? fminf(v0, o0) : fmaxf(v0, o0);                     \
                   v1 = km ? fminf(v1, o1) : fmaxf(v1, o1); }
        FS(2,1)
        FS(4,2) FS(4,1)
        FS(8,4) FS(8,2) FS(8,1)
        FS(16,8) FS(16,4) FS(16,2) FS(16,1)
        FS(32,16) FS(32,8) FS(32,4) FS(32,2) FS(32,1)
        FS(64,32) FS(64,16) FS(64,8) FS(64,4) FS(64,2) FS(64,1)
#undef FS
        if (lane < 16) {
            smA[pr][H][2 * t][lane]     = v0;   // pair-local index
            smA[pr][H][2 * t + 1][lane] = v1;
        }
    }
    __syncthreads();

    // ================= phase 2: merge threshold + collect (ILP-2) ==========
#pragma unroll 1
    for (int t = 0; t < 4; ++t) {
        const int q0 = 2 * t, q1 = q0 + 1;           // pair-local query ids
        // union-16th of the two sorted 16-lists: min_i max(A[i-1], B[15-i])
        float a0 = -INFF, a1 = -INFF, b0v = -INFF, b1v = -INFF;
        if (lane > 0 && lane <= 16) {
            a0 = smA[pr][0][q0][lane - 1];
            a1 = smA[pr][0][q1][lane - 1];
        }
        if (lane < 16) {
            b0v = smA[pr][1][q0][15 - lane];
            b1v = smA[pr][1][q1][15 - lane];
        }
        float m0 = (lane <= 16) ? fmaxf(a0, b0v) : INFF;
        float m1 = (lane <= 16) ? fmaxf(a1, b1v) : INFF;
        m0 = fminf(m0, fxor<1>(m0));   m1 = fminf(m1, fxor<1>(m1));
        m0 = fminf(m0, fxor<2>(m0));   m1 = fminf(m1, fxor<2>(m1));
        m0 = fminf(m0, fxor<4>(m0));   m1 = fminf(m1, fxor<4>(m1));
        m0 = fminf(m0, fxor<8>(m0));   m1 = fminf(m1, fxor<8>(m1));
        m0 = fminf(m0, fxor<16>(m0));  m1 = fminf(m1, fxor<16>(m1));
        m0 = fminf(m0, fxor<32>(m0));  m1 = fminf(m1, fxor<32>(m1));

        const int qg0 = pr * 8 + q0, qg1 = pr * 8 + q1;
        const float Q0x = qshare[0][qg0], Q0y = qshare[1][qg0], Q0z = qshare[2][qg0];
        const float Q1x = qshare[0][qg1], Q1y = qshare[1][qg1], Q1z = qshare[2][qg1];
        const float qq0 = fmaf(Q0z, Q0z, fmaf(Q0y, Q0y, Q0x * Q0x));
        const float qq1 = fmaf(Q1z, Q1z, fmaf(Q1y, Q1y, Q1x * Q1x));
        const float T0 = (m0 + qq0) * (1.0f + 1e-5f) + 1e-4f;
        const float T1 = (m1 + qq1) * (1.0f + 1e-5f) + 1e-4f;

        // exact d2 (reference association), collect <= T
#pragma unroll
        for (int jj = 0; jj < 16; ++jj) {
            const int c = H * 1024 + jj * 64 + lane;
            const float dx0 = __fsub_rn(Q0x, cx[jj]);
            const float dy0 = __fsub_rn(Q0y, cy[jj]);
            const float dz0 = __fsub_rn(Q0z, cz[jj]);
            const float d20 = __fadd_rn(__fadd_rn(__fmul_rn(dx0, dx0), __fmul_rn(dy0, dy0)),
                                        __fmul_rn(dz0, dz0));
            if (d20 <= T0) {
                const int slot = atomicAdd(&cnt[pr][q0], 1);
                if (slot < CAP)
                    buf[pr][q0][slot] = ((u64)__float_as_uint(d20) << 32) | (unsigned)c;
            }
            const float dx1 = __fsub_rn(Q1x, cx[jj]);
            const float dy1 = __fsub_rn(Q1y, cy[jj]);
            const float dz1 = __fsub_rn(Q1z, cz[jj]);
            const float d21 = __fadd_rn(__fadd_rn(__fmul_rn(dx1, dx1), __fmul_rn(dy1, dy1)),
                                        __fmul_rn(dz1, dz1));
            if (d21 <= T1) {
                const int slot = atomicAdd(&cnt[pr][q1], 1);
                if (slot < CAP)
                    buf[pr][q1][slot] = ((u64)__float_as_uint(d21) << 32) | (unsigned)c;
            }
        }
    }
    __syncthreads();

    // ================= phase 3: select top-16 (ILP-2, 2 iters/wave) ========
#pragma unroll 1
    for (int s = 0; s < 2; ++s) {
        const int q0 = H * 4 + 2 * s, q1 = q0 + 1;   // wave's select queries
        const int n0 = min(cnt[pr][q0], CAP);
        const int n1 = min(cnt[pr][q1], CAP);
        u64 k0 = (lane < n0) ? buf[pr][q0][lane] : ~0ULL;
        u64 k1 = (lane < n1) ? buf[pr][q1][lane] : ~0ULL;
#define US(K, J) { const u64 o0 = uxor<J>(k0), o1 = uxor<J>(k1);                \
                   const bool km = (((lane & J) == 0) == ((lane & K) == 0));    \
                   const u64 l0 = k0 < o0 ? k0 : o0, h0 = k0 < o0 ? o0 : k0;    \
                   k0 = km ? l0 : h0;                                           \
                   const u64 l1 = k1 < o1 ? k1 : o1, h1 = k1 < o1 ? o1 : k1;    \
                   k1 = km ? l1 : h1; }
        US(2,1)
        US(4,2) US(4,1)
        US(8,4) US(8,2) US(8,1)
        US(16,8) US(16,4) US(16,2) US(16,1)
        US(32,16) US(32,8) US(32,4) US(32,2) US(32,1)
        US(64,32) US(64,16) US(64,8) US(64,4) US(64,2) US(64,1)
#undef US
        if (lane < KNN_K) {
            knn_out[((size_t)b0 + qblk * 32 + pr * 8 + q0) * KNN_K + lane] =
                b0 + (int)(unsigned)(k0 & 0xffffffffu);
            knn_out[((size_t)b0 + qblk * 32 + pr * 8 + q1) * KNN_K + lane] =
                b0 + (int)(unsigned)(k1 & 0xffffffffu);
        }
    }
}

// ---------------------------------------------------------------------------
// Per-point pre-projection: w[p] = ba + hin[p]@Wa_h + pos[p]@Wa_s,
// v[p] = pos[p]@Wa_s. (x@Wa with x=concat(h_j, p_j-p_i) == w[j] - v[i].)
// ---------------------------------------------------------------------------
template <int CH>
__global__ __launch_bounds__(256) void pre_kernel(
    const float* __restrict__ pos, const float* __restrict__ hin,
    const float* __restrict__ Wa, const float* __restrict__ ba,
    float* __restrict__ w, float* __restrict__ v)
{
    const int gth = blockIdx.x * 256 + threadIdx.x;
    const int p   = gth >> 3;
    const int i8  = gth & 7;
    const float4* Wa4 = (const float4*)Wa;
    const float4* ba4 = (const float4*)ba;

    float4 acc = ba4[i8];
    const float* hrow = hin + (size_t)p * CH;
#pragma unroll
    for (int d = 0; d < CH; ++d) {
        const float h = hrow[d];
        const float4 wr = Wa4[d * 8 + i8];
        acc.x = fmaf(h, wr.x, acc.x);
        acc.y = fmaf(h, wr.y, acc.y);
        acc.z = fmaf(h, wr.z, acc.z);
        acc.w = fmaf(h, wr.w, acc.w);
    }
    float4 vs = make_float4(0.f, 0.f, 0.f, 0.f);
    const float* prow = pos + (size_t)p * 3;
#pragma unroll
    for (int d = 0; d < 3; ++d) {
        const float pd = prow[d];
        const float4 wr = Wa4[(CH + d) * 8 + i8];
        vs.x = fmaf(pd, wr.x, vs.x);
        vs.y = fmaf(pd, wr.y, vs.y);
        vs.z = fmaf(pd, wr.z, vs.z);
        vs.w = fmaf(pd, wr.w, vs.w);
    }
    ((float4*)w)[(size_t)p * 8 + i8] =
        make_float4(acc.x + vs.x, acc.y + vs.y, acc.z + vs.z, acc.w + vs.w);
    ((float4*)v)[(size_t)p * 8 + i8] = vs;
}

// ---------------------------------------------------------------------------
// Edge-MLP layer: lane = edge (p,k); hid = relu(w[j]-v[p]); o[32] register
// accumulator, Wb read as contiguous wave-uniform rows (s_load). Max over the
// 16 edge-lanes via DPP (VALU pipe).
// ---------------------------------------------------------------------------
__global__ __launch_bounds__(256) void layer_kernel(
    const int*   __restrict__ knn,
    const float* __restrict__ Wb, const float* __restrict__ bb,
    const float* __restrict__ w,  const float* __restrict__ v,
    float* __restrict__ hout)
{
    const int gth = blockIdx.x * 256 + threadIdx.x;
    const int p = gth >> 4;
    const int k = gth & 15;
    const int j = knn[gth];

    const float4* w4 = (const float4*)w;
    const float4* v4 = (const float4*)v;

    float hid[32];
#pragma unroll
    for (int i = 0; i < 8; ++i) {
        const float4 a = w4[(size_t)j * 8 + i];
        const float4 b = v4[(size_t)p * 8 + i];
        hid[4 * i + 0] = fmaxf(a.x - b.x, 0.0f);
        hid[4 * i + 1] = fmaxf(a.y - b.y, 0.0f);
        hid[4 * i + 2] = fmaxf(a.z - b.z, 0.0f);
        hid[4 * i + 3] = fmaxf(a.w - b.w, 0.0f);
    }

    float o[32];
#pragma unroll
    for (int c2 = 0; c2 < 32; ++c2) o[c2] = bb[c2];
#pragma unroll
    for (int c = 0; c < 32; ++c) {
        const float hc = hid[c];
        const float* row = Wb + c * 32;   // contiguous, wave-uniform -> s_load
#pragma unroll
        for (int c2 = 0; c2 < 32; ++c2) o[c2] = fmaf(hc, row[c2], o[c2]);
    }

    float out0 = 0.0f, out1 = 0.0f;
#pragma unroll
    for (int c2 = 0; c2 < 32; ++c2) {
        const float s = dpp_max16(o[c2]);
        if ((c2 & 15) == k) { if (c2 < 16) out0 = s; else out1 = s; }
    }
    hout[(size_t)p * 32 + k]      = fmaxf(out0, 0.0f);
    hout[(size_t)p * 32 + 16 + k] = fmaxf(out1, 0.0f);
}

// ---------------------------------------------------------------------------
// Global max pool over each cloud + linear classifier. 1 block per cloud.
// ---------------------------------------------------------------------------
__global__ __launch_bounds__(256) void pool_kernel(
    const float* __restrict__ h2, const float* __restrict__ Wc,
    const float* __restrict__ bc, float* __restrict__ out)
{
    __shared__ float red[8][32];
    __shared__ float sg[32];
    const int cloud = blockIdx.x;
    const int t = threadIdx.x;
    const int c = t & 31, row = t >> 5;
    float m = 0.0f;  // h2 >= 0 after relu
    for (int p = row; p < N_PER; p += 8)
        m = fmaxf(m, h2[((size_t)cloud * N_PER + p) * 32 + c]);
    red[row][c] = m;
    __syncthreads();
    if (t < 32) {
        float gv = red[0][t];
#pragma unroll
        for (int r = 1; r < 8; ++r) gv = fmaxf(gv, red[r][t]);
        sg[t] = gv;
    }
    __syncthreads();
    if (t < 10) {
        float s = bc[t];
#pragma unroll
        for (int c0 = 0; c0 < 32; ++c0) s = fmaf(sg[c0], Wc[c0 * 10 + t], s);
        out[cloud * 10 + t] = s;
    }
}

extern "C" void kernel_launch(void* const* d_in, const int* in_sizes, int n_in,
                              void* d_out, int out_size, void* d_ws, size_t ws_size,
                              hipStream_t stream)
{
    const float* pos = (const float*)d_in[0];
    const float* W1a = (const float*)d_in[2];
    const float* b1a = (const float*)d_in[3];
    const float* W1b = (const float*)d_in[4];
    const float* b1b = (const float*)d_in[5];
    const float* W2a = (const float*)d_in[6];
    const float* b2a = (const float*)d_in[7];
    const float* W2b = (const float*)d_in[8];
    const float* b2b = (const float*)d_in[9];
    const float* Wc  = (const float*)d_in[10];
    const float* bc  = (const float*)d_in[11];

    int*   knn = (int*)d_ws;                                   // 2 MB
    float* w   = (float*)((char*)d_ws + (size_t)(2  << 20));   // 4 MB
    float* v   = (float*)((char*)d_ws + (size_t)(6  << 20));   // 4 MB
    float* h1  = (float*)((char*)d_ws + (size_t)(10 << 20));   // 4 MB
    float* h2  = h1;   // h1 dead after pre2; layer2 reads only w,v
    float* out = (float*)d_out;

    const int npts = NCLOUDS * N_PER;

    knn_kernel<<<dim3(NCLOUDS * 64), dim3(512), 0, stream>>>(pos, knn);
    pre_kernel<3><<<dim3(npts * 8 / 256), dim3(256), 0, stream>>>(
        pos, pos, W1a, b1a, w, v);
    layer_kernel<<<dim3(npts * KNN_K / 256), dim3(256), 0, stream>>>(
        knn, W1b, b1b, w, v, h1);
    pre_kernel<32><<<dim3(npts * 8 / 256), dim3(256), 0, stream>>>(
        pos, h1, W2a, b2a, w, v);
    layer_kernel<<<dim3(npts * KNN_K / 256), dim3(256), 0, stream>>>(
        knn, W2b, b2b, w, v, h2);
    pool_kernel<<<dim3(NCLOUDS), dim3(256), 0, stream>>>(h2, Wc, bc, out);
}